// Round 8
// baseline (5809.505 us; speedup 1.0000x reference)
//
#include <hip/hip_runtime.h>
#include <stdint.h>

// Teacher-forced LSTM, B=64 T=512 D=H=1024.
// a(t) = m(t)*h(t-1) + (1-m(t))*x(t)   (computed in prev step's cell phase)
// gates(t) = [a(t) | h(t-1)] @ [Wx | Wh]^T + bias   -- one K=2048 GEMM
// Persistent: 128 blocks x 512 thr; block owns 8 hidden units (32 gate rows),
// all 64 batches. 8 waves = 2 M-tiles(32 batches) x 4 K-quarters(512 k).
// Weights bf16 LDS-stationary in conflict-free layout [kq][j][kg][n][16B]
// (lane-consecutive ds_read_b128, no swizzle). A-panel abuf[2][b][k] bf16 in
// ws: producers store agent-scope write-through; consumers load via TWO
// monolithic asm blocks (16x global_load_dwordx4 sc1 into pinned v[64:127],
// one s_waitcnt, 16 MFMAs) -> 2 L3 round trips instead of ~13.
// Barrier: per-block flag -> block-0 master polls -> single gen word. No fences.

#define B_ 64
#define T_ 512
#define D_ 1024
#define H_ 1024
#define NBLK 128
#define UPB 8
#define NROW 32
#define NTHR 512

typedef __attribute__((ext_vector_type(8))) short short8;
typedef __attribute__((ext_vector_type(16))) float f32x16;

// LDS (bytes): W 131072 @0 | gbuf float[2][64][33] @131072 | bias @147968
#define GBUF_OFF 131072
#define BIAS_OFF 147968
#define SMEM_BYTES 148096

// ws (bytes): flags[128] u32 @0 | gen u32 @2048 | abuf @4096: [2][64 b][2048 k] bf16
#define WS_ABUF 4096
#define ABUF_HALF (64 * 2048) /* shorts per buffer (256KB) */

__device__ __forceinline__ unsigned f2bf(float f) {  // fp32 -> bf16 RNE
  unsigned u = __float_as_uint(f);
  return (u + 0x7FFFu + ((u >> 16) & 1u)) >> 16;
}
__device__ __forceinline__ float sigf(float x) { return 1.0f / (1.0f + __expf(-x)); }
__device__ __forceinline__ float tanhf_(float x) { return 1.0f - 2.0f / (__expf(2.0f * x) + 1.0f); }

// a(0) = (1-m(0))*x(0) at k=0..1023; h(0)=0 at k=1024..2047 from memset.
__global__ void prep_a0(const float* __restrict__ x, const float* __restrict__ tm,
                        unsigned short* __restrict__ abuf) {
  int i = blockIdx.x * blockDim.x + threadIdx.x;  // over B_*D_
  if (i >= B_ * D_) return;
  int d = i & (D_ - 1), b = i >> 10;
  float m = tm[b * T_];
  float a = (1.0f - m) * x[(size_t)b * T_ * D_ + d];
  abuf[b * 2048 + d] = (unsigned short)f2bf(a);
}

__global__ __launch_bounds__(NTHR, 1)
void lstm_persist(const float* __restrict__ xf,
                  const float* __restrict__ tm,
                  const float* __restrict__ Wx, const float* __restrict__ bxp,
                  const float* __restrict__ Wh, const float* __restrict__ bhp,
                  float* __restrict__ out,
                  unsigned short* __restrict__ abuf,
                  unsigned* __restrict__ flags,
                  unsigned* __restrict__ gen)
{
  extern __shared__ char smem[];
  float* gbuf     = (float*)(smem + GBUF_OFF);  // [2][64][33]
  float* bias_lds = (float*)(smem + BIAS_OFF);

  const int tid = threadIdx.x;
  const int bid = blockIdx.x;

  // ---- stage weights -> LDS, conflict-free layout ----
  // dword slot s (0..32767): dw=s&3, n=(s>>2)&31, kg=(s>>7)&1, j=(s>>8)&31, kq=s>>13
  // byte addr = s*4 = kq*32768 + j*1024 + kg*512 + n*16 + dw*4
  // source: gate-row n -> grow=(n>>3)*H + bid*8 + (n&7); k = kq*512+j*16+kg*8+dw*2
  for (int i = 0; i < 64; ++i) {
    const int s  = i * NTHR + tid;
    const int dw = s & 3, n = (s >> 2) & 31, kgs = (s >> 7) & 1;
    const int js = (s >> 8) & 31, kqs = s >> 13;
    const int grow = (n >> 3) * H_ + bid * UPB + (n & 7);
    const int k = kqs * 512 + js * 16 + kgs * 8 + dw * 2;
    const float* src = (k < D_) ? (Wx + (size_t)grow * D_ + k)
                                : (Wh + (size_t)grow * H_ + (k - D_));
    float2 v = *(const float2*)src;
    *(unsigned*)(smem + (size_t)s * 4) = f2bf(v.x) | (f2bf(v.y) << 16);
  }
  if (tid < NROW) {
    const int grow = (tid >> 3) * H_ + bid * UPB + (tid & 7);
    bias_lds[tid] = bxp[grow] + bhp[grow];
  }

  const int lane = tid & 63;
  const int wid  = tid >> 6;   // 0..7
  const int mt   = wid >> 2;   // M-tile (32 batch rows)
  const int kq   = wid & 3;    // K-quarter of 2048 (512 each)
  const int l31  = lane & 31;  // batch row within M-tile (A) / gate row (B)
  const int kg   = lane >> 5;  // 0..1
  const int m0   = mt * 32;

  // weight LDS per-lane base: kq*32768 + kg*512 + l31*16 (+ j*1024)
  const unsigned wbase = (unsigned)(kq * 32768 + kg * 512 + l31 * 16);
  // A per-lane byte base inside a buffer: (m0+l31)*4096 + kq*1024 + kg*16 (+ j*32)
  const size_t abase = (size_t)(m0 + l31) * 4096 + (unsigned)(kq * 1024 + kg * 16);

  const int cb = tid >> 3;  // cell: batch (0..63)
  const int cu = tid & 7;   // cell: unit within block
  const int hu = bid * UPB + cu;
  float ccell = 0.0f, hv = 0.0f;

  unsigned cur = 0;
  __syncthreads();

  for (int t = 0; t < T_; ++t) {
    const int nxt = (t + 1 < T_) ? (t + 1) : t;
    const unsigned tgt = (unsigned)(t + 1);

    const unsigned long long pA = (unsigned long long)(uintptr_t)
        ((const char*)abuf + (size_t)cur * (ABUF_HALF * 2) + abase);

#define LDW(J) (*(const short8*)(smem + wbase + (unsigned)((J) * 1024)))
    f32x16 acc = {0,0,0,0,0,0,0,0,0,0,0,0,0,0,0,0};

    {  // ---- first 16 k-frags: 16 batched loads -> pinned v[64:127], 16 MFMAs ----
      short8 w0 = LDW(0), w1 = LDW(1), w2 = LDW(2), w3 = LDW(3);
      short8 w4 = LDW(4), w5 = LDW(5), w6 = LDW(6), w7 = LDW(7);
      short8 w8 = LDW(8), w9 = LDW(9), w10 = LDW(10), w11 = LDW(11);
      short8 w12 = LDW(12), w13 = LDW(13), w14 = LDW(14), w15 = LDW(15);
      asm volatile(
        "global_load_dwordx4 v[64:67],   %[pa], off sc1\n\t"
        "global_load_dwordx4 v[68:71],   %[pa], off offset:32 sc1\n\t"
        "global_load_dwordx4 v[72:75],   %[pa], off offset:64 sc1\n\t"
        "global_load_dwordx4 v[76:79],   %[pa], off offset:96 sc1\n\t"
        "global_load_dwordx4 v[80:83],   %[pa], off offset:128 sc1\n\t"
        "global_load_dwordx4 v[84:87],   %[pa], off offset:160 sc1\n\t"
        "global_load_dwordx4 v[88:91],   %[pa], off offset:192 sc1\n\t"
        "global_load_dwordx4 v[92:95],   %[pa], off offset:224 sc1\n\t"
        "global_load_dwordx4 v[96:99],   %[pa], off offset:256 sc1\n\t"
        "global_load_dwordx4 v[100:103], %[pa], off offset:288 sc1\n\t"
        "global_load_dwordx4 v[104:107], %[pa], off offset:320 sc1\n\t"
        "global_load_dwordx4 v[108:111], %[pa], off offset:352 sc1\n\t"
        "global_load_dwordx4 v[112:115], %[pa], off offset:384 sc1\n\t"
        "global_load_dwordx4 v[116:119], %[pa], off offset:416 sc1\n\t"
        "global_load_dwordx4 v[120:123], %[pa], off offset:448 sc1\n\t"
        "global_load_dwordx4 v[124:127], %[pa], off offset:480 sc1\n\t"
        "s_waitcnt vmcnt(0)\n\t"
        "v_mfma_f32_32x32x16_bf16 %[acc], v[64:67],   %[w0],  %[acc]\n\t"
        "v_mfma_f32_32x32x16_bf16 %[acc], v[68:71],   %[w1],  %[acc]\n\t"
        "v_mfma_f32_32x32x16_bf16 %[acc], v[72:75],   %[w2],  %[acc]\n\t"
        "v_mfma_f32_32x32x16_bf16 %[acc], v[76:79],   %[w3],  %[acc]\n\t"
        "v_mfma_f32_32x32x16_bf16 %[acc], v[80:83],   %[w4],  %[acc]\n\t"
        "v_mfma_f32_32x32x16_bf16 %[acc], v[84:87],   %[w5],  %[acc]\n\t"
        "v_mfma_f32_32x32x16_bf16 %[acc], v[88:91],   %[w6],  %[acc]\n\t"
        "v_mfma_f32_32x32x16_bf16 %[acc], v[92:95],   %[w7],  %[acc]\n\t"
        "v_mfma_f32_32x32x16_bf16 %[acc], v[96:99],   %[w8],  %[acc]\n\t"
        "v_mfma_f32_32x32x16_bf16 %[acc], v[100:103], %[w9],  %[acc]\n\t"
        "v_mfma_f32_32x32x16_bf16 %[acc], v[104:107], %[w10], %[acc]\n\t"
        "v_mfma_f32_32x32x16_bf16 %[acc], v[108:111], %[w11], %[acc]\n\t"
        "v_mfma_f32_32x32x16_bf16 %[acc], v[112:115], %[w12], %[acc]\n\t"
        "v_mfma_f32_32x32x16_bf16 %[acc], v[116:119], %[w13], %[acc]\n\t"
        "v_mfma_f32_32x32x16_bf16 %[acc], v[120:123], %[w14], %[acc]\n\t"
        "v_mfma_f32_32x32x16_bf16 %[acc], v[124:127], %[w15], %[acc]"
        : [acc] "+v"(acc)
        : [pa] "v"(pA),
          [w0] "v"(w0), [w1] "v"(w1), [w2] "v"(w2), [w3] "v"(w3),
          [w4] "v"(w4), [w5] "v"(w5), [w6] "v"(w6), [w7] "v"(w7),
          [w8] "v"(w8), [w9] "v"(w9), [w10] "v"(w10), [w11] "v"(w11),
          [w12] "v"(w12), [w13] "v"(w13), [w14] "v"(w14), [w15] "v"(w15)
        : "memory",
          "v64","v65","v66","v67","v68","v69","v70","v71",
          "v72","v73","v74","v75","v76","v77","v78","v79",
          "v80","v81","v82","v83","v84","v85","v86","v87",
          "v88","v89","v90","v91","v92","v93","v94","v95",
          "v96","v97","v98","v99","v100","v101","v102","v103",
          "v104","v105","v106","v107","v108","v109","v110","v111",
          "v112","v113","v114","v115","v116","v117","v118","v119",
          "v120","v121","v122","v123","v124","v125","v126","v127");
    }
    {  // ---- second 16 k-frags (byte offsets 512..992) ----
      short8 w0 = LDW(16), w1 = LDW(17), w2 = LDW(18), w3 = LDW(19);
      short8 w4 = LDW(20), w5 = LDW(21), w6 = LDW(22), w7 = LDW(23);
      short8 w8 = LDW(24), w9 = LDW(25), w10 = LDW(26), w11 = LDW(27);
      short8 w12 = LDW(28), w13 = LDW(29), w14 = LDW(30), w15 = LDW(31);
      asm volatile(
        "global_load_dwordx4 v[64:67],   %[pa], off offset:512 sc1\n\t"
        "global_load_dwordx4 v[68:71],   %[pa], off offset:544 sc1\n\t"
        "global_load_dwordx4 v[72:75],   %[pa], off offset:576 sc1\n\t"
        "global_load_dwordx4 v[76:79],   %[pa], off offset:608 sc1\n\t"
        "global_load_dwordx4 v[80:83],   %[pa], off offset:640 sc1\n\t"
        "global_load_dwordx4 v[84:87],   %[pa], off offset:672 sc1\n\t"
        "global_load_dwordx4 v[88:91],   %[pa], off offset:704 sc1\n\t"
        "global_load_dwordx4 v[92:95],   %[pa], off offset:736 sc1\n\t"
        "global_load_dwordx4 v[96:99],   %[pa], off offset:768 sc1\n\t"
        "global_load_dwordx4 v[100:103], %[pa], off offset:800 sc1\n\t"
        "global_load_dwordx4 v[104:107], %[pa], off offset:832 sc1\n\t"
        "global_load_dwordx4 v[108:111], %[pa], off offset:864 sc1\n\t"
        "global_load_dwordx4 v[112:115], %[pa], off offset:896 sc1\n\t"
        "global_load_dwordx4 v[116:119], %[pa], off offset:928 sc1\n\t"
        "global_load_dwordx4 v[120:123], %[pa], off offset:960 sc1\n\t"
        "global_load_dwordx4 v[124:127], %[pa], off offset:992 sc1\n\t"
        "s_waitcnt vmcnt(0)\n\t"
        "v_mfma_f32_32x32x16_bf16 %[acc], v[64:67],   %[w0],  %[acc]\n\t"
        "v_mfma_f32_32x32x16_bf16 %[acc], v[68:71],   %[w1],  %[acc]\n\t"
        "v_mfma_f32_32x32x16_bf16 %[acc], v[72:75],   %[w2],  %[acc]\n\t"
        "v_mfma_f32_32x32x16_bf16 %[acc], v[76:79],   %[w3],  %[acc]\n\t"
        "v_mfma_f32_32x32x16_bf16 %[acc], v[80:83],   %[w4],  %[acc]\n\t"
        "v_mfma_f32_32x32x16_bf16 %[acc], v[84:87],   %[w5],  %[acc]\n\t"
        "v_mfma_f32_32x32x16_bf16 %[acc], v[88:91],   %[w6],  %[acc]\n\t"
        "v_mfma_f32_32x32x16_bf16 %[acc], v[92:95],   %[w7],  %[acc]\n\t"
        "v_mfma_f32_32x32x16_bf16 %[acc], v[96:99],   %[w8],  %[acc]\n\t"
        "v_mfma_f32_32x32x16_bf16 %[acc], v[100:103], %[w9],  %[acc]\n\t"
        "v_mfma_f32_32x32x16_bf16 %[acc], v[104:107], %[w10], %[acc]\n\t"
        "v_mfma_f32_32x32x16_bf16 %[acc], v[108:111], %[w11], %[acc]\n\t"
        "v_mfma_f32_32x32x16_bf16 %[acc], v[112:115], %[w12], %[acc]\n\t"
        "v_mfma_f32_32x32x16_bf16 %[acc], v[116:119], %[w13], %[acc]\n\t"
        "v_mfma_f32_32x32x16_bf16 %[acc], v[120:123], %[w14], %[acc]\n\t"
        "v_mfma_f32_32x32x16_bf16 %[acc], v[124:127], %[w15], %[acc]"
        : [acc] "+v"(acc)
        : [pa] "v"(pA),
          [w0] "v"(w0), [w1] "v"(w1), [w2] "v"(w2), [w3] "v"(w3),
          [w4] "v"(w4), [w5] "v"(w5), [w6] "v"(w6), [w7] "v"(w7),
          [w8] "v"(w8), [w9] "v"(w9), [w10] "v"(w10), [w11] "v"(w11),
          [w12] "v"(w12), [w13] "v"(w13), [w14] "v"(w14), [w15] "v"(w15)
        : "memory",
          "v64","v65","v66","v67","v68","v69","v70","v71",
          "v72","v73","v74","v75","v76","v77","v78","v79",
          "v80","v81","v82","v83","v84","v85","v86","v87",
          "v88","v89","v90","v91","v92","v93","v94","v95",
          "v96","v97","v98","v99","v100","v101","v102","v103",
          "v104","v105","v106","v107","v108","v109","v110","v111",
          "v112","v113","v114","v115","v116","v117","v118","v119",
          "v120","v121","v122","v123","v124","v125","v126","v127");
    }
#undef LDW

    // ---- cell operands for t+1 (issued after asm; overlap epilogue) ----
    const float mv = tm[cb * T_ + nxt];
    const float xv = xf[((size_t)cb * T_ + nxt) * D_ + hu];

    // ---- cross-kq reduce: kq even writes slab, kq odd adds ----
    // C layout (32x32): col = lane&31, row = (e&3) + 8*(e>>2) + 4*(lane>>5)
    const int s = kq >> 1;
    if ((kq & 1) == 0) {
#pragma unroll
      for (int e = 0; e < 16; ++e) {
        const int br = m0 + (e & 3) + 8 * (e >> 2) + 4 * kg;
        float g = acc[e];
        if (kq == 0) g += bias_lds[l31];
        gbuf[(s * 64 + br) * 33 + l31] = g;
      }
    }
    __syncthreads();  // (B)
    if (kq & 1) {
#pragma unroll
      for (int e = 0; e < 16; ++e) {
        const int br = m0 + (e & 3) + 8 * (e >> 2) + 4 * kg;
        gbuf[(s * 64 + br) * 33 + l31] += acc[e];
      }
    }
    __syncthreads();  // (C)

    // ---- cell: one (b,u) per thread ----
    {
      const float* g0 = gbuf + cb * 33;
      const float* g1 = gbuf + (64 + cb) * 33;
      const float gi = g0[cu]      + g1[cu];
      const float gf = g0[8 + cu]  + g1[8 + cu];
      const float gg = g0[16 + cu] + g1[16 + cu];
      const float go = g0[24 + cu] + g1[24 + cu];
      const float iv = sigf(gi), fv = sigf(gf), gv = tanhf_(gg), ov = sigf(go);
      ccell = ccell * fv + iv * gv;
      hv = ov * tanhf_(ccell);

      const float av = mv * hv + (1.0f - mv) * xv;  // a(t+1) for (cb, hu)
      unsigned short* dst = abuf + (cur ^ 1u) * ABUF_HALF + cb * 2048;
      __hip_atomic_store(dst + hu, (unsigned short)f2bf(av),
                         __ATOMIC_RELAXED, __HIP_MEMORY_SCOPE_AGENT);
      __hip_atomic_store(dst + 1024 + hu, (unsigned short)f2bf(hv),
                         __ATOMIC_RELAXED, __HIP_MEMORY_SCOPE_AGENT);
    }

    __syncthreads();  // (D) drains a/h stores (vmcnt(0) before s_barrier)

    if (bid == 0) {
      if (wid == 0) {
        const int i0 = 1 + lane;   // 1..64
        const int i1 = 65 + lane;  // 65..127 valid
        for (;;) {
          unsigned v0 = __hip_atomic_load(flags + i0,
                                          __ATOMIC_RELAXED, __HIP_MEMORY_SCOPE_AGENT);
          unsigned v1 = (i1 < NBLK)
                          ? __hip_atomic_load(flags + i1,
                                              __ATOMIC_RELAXED, __HIP_MEMORY_SCOPE_AGENT)
                          : tgt;
          if (__all((v0 >= tgt) && (v1 >= tgt))) break;
          __builtin_amdgcn_s_sleep(1);
        }
        if (lane == 0)
          __hip_atomic_store(gen, tgt, __ATOMIC_RELAXED, __HIP_MEMORY_SCOPE_AGENT);
      }
      out[((size_t)cb * T_ + t) * H_ + hu] = hv;  // off critical path
    } else {
      if (tid == 0)
        __hip_atomic_store(flags + bid, tgt,
                           __ATOMIC_RELAXED, __HIP_MEMORY_SCOPE_AGENT);
      out[((size_t)cb * T_ + t) * H_ + hu] = hv;  // overlaps gen wait
      if (wid == 0) {
        while (__hip_atomic_load(gen, __ATOMIC_RELAXED, __HIP_MEMORY_SCOPE_AGENT) < tgt)
          __builtin_amdgcn_s_sleep(1);
      }
    }
    __syncthreads();  // (E)
    __builtin_amdgcn_sched_barrier(0);  // nothing hoists above the wait

    cur ^= 1u;
  }

  // finals: hn, cn
  out[(size_t)B_ * T_ * H_ + (size_t)cb * H_ + hu] = hv;
  out[(size_t)B_ * T_ * H_ + (size_t)B_ * H_ + (size_t)cb * H_ + hu] = ccell;
}

extern "C" void kernel_launch(void* const* d_in, const int* in_sizes, int n_in,
                              void* d_out, int out_size, void* d_ws, size_t ws_size,
                              hipStream_t stream) {
  const float* x  = (const float*)d_in[0];
  const float* tm = (const float*)d_in[1];
  const float* Wx = (const float*)d_in[2];
  const float* bx = (const float*)d_in[3];
  const float* Wh = (const float*)d_in[4];
  const float* bh = (const float*)d_in[5];
  float* out = (float*)d_out;
  char* ws = (char*)d_ws;

  unsigned* flags      = (unsigned*)ws;
  unsigned* gen        = (unsigned*)(ws + 2048);
  unsigned short* abuf = (unsigned short*)(ws + WS_ABUF);

  // zero flags + gen + both [a|h] buffers (h(0)=0 comes from this)
  hipMemsetAsync(ws, 0, WS_ABUF + 2 * ABUF_HALF * 2, stream);
  prep_a0<<<dim3((B_ * D_ + 255) / 256), dim3(256), 0, stream>>>(x, tm, abuf);
  lstm_persist<<<dim3(NBLK), dim3(NTHR), SMEM_BYTES, stream>>>(
      x, tm, Wx, bx, Wh, bh, out, abuf, flags, gen);
}